// Round 3
// baseline (44.103 us; speedup 1.0000x reference)
//
#include <hip/hip_runtime.h>

// AxonLIFNode: sequential LIF + axon-current recurrence over T.
//   mem   = mem + (x_t + V_RESET - mem) / TAU        (V_RESET=0, TAU=2)
//   spike = (mem - V_TH > 0) ? 1 : 0                 (V_TH=1)
//   mem   = spike ? V_RESET : mem
//   out_i = out_i * sigmoid(w) + spike
// Outputs: spikes [B,T,N], i_pot [B,T,N], concatenated flat.
//
// B=64, T=64, N=4096. Round 1: float4, 1 wave/SIMD -> 34.0us (5.92 TB/s).
// Round 3: float2 per thread (2 waves/SIMD for TLP) + nontemporal
// loads/stores via clang ext_vector_type (HIP_vector_type is rejected by
// the nontemporal builtins).

#define LIF_B 64
#define LIF_T 64
#define LIF_N 4096
#define LIF_N2 (LIF_N / 2)

typedef float v2f __attribute__((ext_vector_type(2)));

__global__ __launch_bounds__(256) void axon_lif_kernel(
    const v2f* __restrict__ X,       // [B, T, N/2]
    const float* __restrict__ wp,    // scalar
    v2f* __restrict__ out_spike,     // [B, T, N/2]
    v2f* __restrict__ out_ipot)      // [B, T, N/2]
{
    const int idx = blockIdx.x * blockDim.x + threadIdx.x;  // over B * N2
    const int b  = idx >> 11;           // / LIF_N2 (2048)
    const int n2 = idx & (LIF_N2 - 1);

    const float w = wp[0];
    const float inv_tau = 1.0f / (1.0f + expf(-w));   // sigmoid(w)

    v2f mem = (v2f)(0.f);
    v2f oi  = (v2f)(0.f);

    const size_t base = (size_t)b * LIF_T * LIF_N2 + n2;

#pragma unroll 8
    for (int t = 0; t < LIF_T; ++t) {
        const size_t a = base + (size_t)t * LIF_N2;
        const v2f x = __builtin_nontemporal_load(&X[a]);
        v2f sp;

        // component-wise LIF step, in the reference's arithmetic order
#define LIF_STEP(c)                                            \
        {                                                      \
            mem[c] = mem[c] + (x[c] + 0.0f - mem[c]) / 2.0f;   \
            const float d = mem[c] - 1.0f;                     \
            const float s = (d > 0.0f) ? 1.0f : 0.0f;          \
            mem[c] = (s > 0.0f) ? 0.0f : mem[c];               \
            oi[c] = oi[c] * inv_tau + s;                       \
            sp[c] = s;                                         \
        }
        LIF_STEP(0)
        LIF_STEP(1)
#undef LIF_STEP

        __builtin_nontemporal_store(sp, &out_spike[a]);
        __builtin_nontemporal_store(oi, &out_ipot[a]);
    }
}

extern "C" void kernel_launch(void* const* d_in, const int* in_sizes, int n_in,
                              void* d_out, int out_size, void* d_ws, size_t ws_size,
                              hipStream_t stream) {
    const float* X = (const float*)d_in[0];
    const float* w = (const float*)d_in[1];
    float* out = (float*)d_out;

    float* spikes = out;                                  // [B,T,N]
    float* ipot   = out + (size_t)LIF_B * LIF_T * LIF_N;  // [B,T,N]

    const int total = LIF_B * LIF_N2;   // 131072 threads
    const int block = 256;
    const int grid  = (total + block - 1) / block;

    axon_lif_kernel<<<grid, block, 0, stream>>>(
        (const v2f*)X, w, (v2f*)spikes, (v2f*)ipot);
}

// Round 4
// 33.837 us; speedup vs baseline: 1.3034x; 1.3034x over previous
//
#include <hip/hip_runtime.h>

// AxonLIFNode: sequential LIF + axon-current recurrence over T.
//   mem   = mem + (x_t + V_RESET - mem) / TAU        (V_RESET=0, TAU=2)
//   spike = (mem - V_TH > 0) ? 1 : 0                 (V_TH=1)
//   mem   = spike ? V_RESET : mem
//   out_i = out_i * sigmoid(w) + spike
// Outputs: spikes [B,T,N], i_pot [B,T,N], concatenated flat.
//
// B=64, T=64, N=4096.
// R1: float4, regular ld/st            -> 34.0 us (5.92 TB/s, 94% copy ceiling)
// R3: float2 + nt ld/st                -> 44.1 us (8B/lane regression; 2 vars at once)
// R4: float4 again, SINGLE delta vs R1: nontemporal STORES only
//     (writes = 2/3 of the 201MB traffic; nt avoids L2 write-allocate
//      polluting the X read stream). Loads stay default.

#define LIF_B 64
#define LIF_T 64
#define LIF_N 4096
#define LIF_N4 (LIF_N / 4)

typedef float v4f __attribute__((ext_vector_type(4)));

__global__ __launch_bounds__(256) void axon_lif_kernel(
    const v4f* __restrict__ X,       // [B, T, N/4]
    const float* __restrict__ wp,    // scalar
    v4f* __restrict__ out_spike,     // [B, T, N/4]
    v4f* __restrict__ out_ipot)      // [B, T, N/4]
{
    const int idx = blockIdx.x * blockDim.x + threadIdx.x;  // over B * N4
    const int b  = idx >> 10;           // / LIF_N4 (1024)
    const int n4 = idx & (LIF_N4 - 1);

    const float w = wp[0];
    const float inv_tau = 1.0f / (1.0f + expf(-w));   // sigmoid(w)

    v4f mem = (v4f)(0.f);
    v4f oi  = (v4f)(0.f);

    const size_t base = (size_t)b * LIF_T * LIF_N4 + n4;

#pragma unroll 8
    for (int t = 0; t < LIF_T; ++t) {
        const size_t a = base + (size_t)t * LIF_N4;
        const v4f x = X[a];
        v4f sp;

        // component-wise LIF step, in the reference's arithmetic order
#define LIF_STEP(c)                                            \
        {                                                      \
            mem[c] = mem[c] + (x[c] + 0.0f - mem[c]) / 2.0f;   \
            const float d = mem[c] - 1.0f;                     \
            const float s = (d > 0.0f) ? 1.0f : 0.0f;          \
            mem[c] = (s > 0.0f) ? 0.0f : mem[c];               \
            oi[c] = oi[c] * inv_tau + s;                       \
            sp[c] = s;                                         \
        }
        LIF_STEP(0)
        LIF_STEP(1)
        LIF_STEP(2)
        LIF_STEP(3)
#undef LIF_STEP

        __builtin_nontemporal_store(sp, &out_spike[a]);
        __builtin_nontemporal_store(oi, &out_ipot[a]);
    }
}

extern "C" void kernel_launch(void* const* d_in, const int* in_sizes, int n_in,
                              void* d_out, int out_size, void* d_ws, size_t ws_size,
                              hipStream_t stream) {
    const float* X = (const float*)d_in[0];
    const float* w = (const float*)d_in[1];
    float* out = (float*)d_out;

    float* spikes = out;                                  // [B,T,N]
    float* ipot   = out + (size_t)LIF_B * LIF_T * LIF_N;  // [B,T,N]

    const int total = LIF_B * LIF_N4;   // 65536 threads
    const int block = 256;
    const int grid  = (total + block - 1) / block;

    axon_lif_kernel<<<grid, block, 0, stream>>>(
        (const v4f*)X, w, (v4f*)spikes, (v4f*)ipot);
}

// Round 5
// 33.381 us; speedup vs baseline: 1.3212x; 1.0136x over previous
//
#include <hip/hip_runtime.h>

// AxonLIFNode: sequential LIF + axon-current recurrence over T.
//   mem   = mem + (x_t + V_RESET - mem) / TAU        (V_RESET=0, TAU=2)
//   spike = (mem - V_TH > 0) ? 1 : 0                 (V_TH=1)
//   mem   = spike ? V_RESET : mem
//   out_i = out_i * sigmoid(w) + spike
// Outputs: spikes [B,T,N], i_pot [B,T,N], concatenated flat.
//
// B=64, T=64, N=4096.
// R1: float4, regular ld/st        -> 34.0 us (5.92 TB/s)
// R3: float2 + nt ld/st            -> 44.1 us (8B/lane regression)
// R4: float4 + nt stores           -> 33.8 us (nt-store neutral)
// R5: SINGLE delta vs R4: unroll 8 -> 16 (deeper load batch / fewer
//     waitcnt chain points per wave; MLP was the last candidate limiter).

#define LIF_B 64
#define LIF_T 64
#define LIF_N 4096
#define LIF_N4 (LIF_N / 4)

typedef float v4f __attribute__((ext_vector_type(4)));

__global__ __launch_bounds__(256) void axon_lif_kernel(
    const v4f* __restrict__ X,       // [B, T, N/4]
    const float* __restrict__ wp,    // scalar
    v4f* __restrict__ out_spike,     // [B, T, N/4]
    v4f* __restrict__ out_ipot)      // [B, T, N/4]
{
    const int idx = blockIdx.x * blockDim.x + threadIdx.x;  // over B * N4
    const int b  = idx >> 10;           // / LIF_N4 (1024)
    const int n4 = idx & (LIF_N4 - 1);

    const float w = wp[0];
    const float inv_tau = 1.0f / (1.0f + expf(-w));   // sigmoid(w)

    v4f mem = (v4f)(0.f);
    v4f oi  = (v4f)(0.f);

    const size_t base = (size_t)b * LIF_T * LIF_N4 + n4;

#pragma unroll 16
    for (int t = 0; t < LIF_T; ++t) {
        const size_t a = base + (size_t)t * LIF_N4;
        const v4f x = X[a];
        v4f sp;

        // component-wise LIF step, in the reference's arithmetic order
#define LIF_STEP(c)                                            \
        {                                                      \
            mem[c] = mem[c] + (x[c] + 0.0f - mem[c]) / 2.0f;   \
            const float d = mem[c] - 1.0f;                     \
            const float s = (d > 0.0f) ? 1.0f : 0.0f;          \
            mem[c] = (s > 0.0f) ? 0.0f : mem[c];               \
            oi[c] = oi[c] * inv_tau + s;                       \
            sp[c] = s;                                         \
        }
        LIF_STEP(0)
        LIF_STEP(1)
        LIF_STEP(2)
        LIF_STEP(3)
#undef LIF_STEP

        __builtin_nontemporal_store(sp, &out_spike[a]);
        __builtin_nontemporal_store(oi, &out_ipot[a]);
    }
}

extern "C" void kernel_launch(void* const* d_in, const int* in_sizes, int n_in,
                              void* d_out, int out_size, void* d_ws, size_t ws_size,
                              hipStream_t stream) {
    const float* X = (const float*)d_in[0];
    const float* w = (const float*)d_in[1];
    float* out = (float*)d_out;

    float* spikes = out;                                  // [B,T,N]
    float* ipot   = out + (size_t)LIF_B * LIF_T * LIF_N;  // [B,T,N]

    const int total = LIF_B * LIF_N4;   // 65536 threads
    const int block = 256;
    const int grid  = (total + block - 1) / block;

    axon_lif_kernel<<<grid, block, 0, stream>>>(
        (const v4f*)X, w, (v4f*)spikes, (v4f*)ipot);
}